// Round 1
// baseline (161.043 us; speedup 1.0000x reference)
//
#include <hip/hip_runtime.h>

#define NN 2304
#define CC 256
#define HH 8
#define HD 32
#define NYY 48
#define SCALE 0.17677669529663687f

typedef __bf16 bf16_t;
typedef __bf16 bf8v __attribute__((ext_vector_type(8)));
typedef float f4v __attribute__((ext_vector_type(4)));

__device__ __forceinline__ f4v mfma16(bf8v a, bf8v b, f4v c) {
    return __builtin_amdgcn_mfma_f32_16x16x32_bf16(a, b, c, 0, 0, 0);
}

// ---------------------------------------------------------------------------
// Kernel 1: transpose-convert x (256 x 2304 f32) -> xT (2304 x 256 bf16)
// ---------------------------------------------------------------------------
__global__ __launch_bounds__(256) void k_xT(const float* __restrict__ x,
                                            bf16_t* __restrict__ xT) {
    __shared__ float tile[64][33];
    const int c0 = (blockIdx.x & 7) * 32;
    const int n0 = (blockIdx.x >> 3) * 64;
    const int t = threadIdx.x;
    const int n = t & 63, cb = t >> 6;  // cb in 0..3
#pragma unroll
    for (int cc = 0; cc < 8; cc++) {
        int c = cc * 4 + cb;
        tile[n][c] = x[(size_t)(c0 + c) * NN + n0 + n];
    }
    __syncthreads();
    const int c = t & 31, nb = t >> 5;  // nb in 0..7
#pragma unroll
    for (int nn = 0; nn < 8; nn++) {
        int n2 = nn * 8 + nb;
        xT[(size_t)(n0 + n2) * CC + c0 + c] = (bf16_t)tile[n2][c];
    }
}

// ---------------------------------------------------------------------------
// Kernel 2: QKV projection GEMM (M=256 o, N=2304 n, K=256 c), bf16 MFMA.
//   Q -> Qt (H, N, 32)  pre-scaled by SCALE
//   K -> Kt (H, N, 32)
//   V -> Vd (H, 32, N)
// ---------------------------------------------------------------------------
__global__ __launch_bounds__(256) void k_proj_qkv(
    const float* __restrict__ Wq, const float* __restrict__ bq,
    const float* __restrict__ Wk, const float* __restrict__ bk,
    const float* __restrict__ Wv, const float* __restrict__ bv,
    const bf16_t* __restrict__ xT,
    bf16_t* __restrict__ Qt, bf16_t* __restrict__ Kt, bf16_t* __restrict__ Vd) {
    const int mat = blockIdx.z;
    const float* W = (mat == 0) ? Wq : (mat == 1) ? Wk : Wv;
    const float* bias = (mat == 0) ? bq : (mat == 1) ? bk : bv;
    const int n0 = blockIdx.x * 64;
    const int o0 = blockIdx.y * 64;
    const int lane = threadIdx.x & 63;
    const int wave = threadIdx.x >> 6;
    const int l15 = lane & 15;
    const int quad = lane >> 4;
    const int orow = o0 + wave * 16;

    f4v acc[4];
#pragma unroll
    for (int i = 0; i < 4; i++) acc[i] = f4v{0.f, 0.f, 0.f, 0.f};

    for (int k0 = 0; k0 < CC; k0 += 32) {
        const float* wp = W + (size_t)(orow + l15) * CC + k0 + quad * 8;
        float4 wa = *(const float4*)wp;
        float4 wb = *(const float4*)(wp + 4);
        bf8v af;
        af[0] = (bf16_t)wa.x; af[1] = (bf16_t)wa.y;
        af[2] = (bf16_t)wa.z; af[3] = (bf16_t)wa.w;
        af[4] = (bf16_t)wb.x; af[5] = (bf16_t)wb.y;
        af[6] = (bf16_t)wb.z; af[7] = (bf16_t)wb.w;
#pragma unroll
        for (int nb = 0; nb < 4; nb++) {
            bf8v bfv = *(const bf8v*)(xT + (size_t)(n0 + nb * 16 + l15) * CC + k0 + quad * 8);
            acc[nb] = mfma16(af, bfv, acc[nb]);
        }
    }

#pragma unroll
    for (int r = 0; r < 4; r++) {
        const int o = orow + quad * 4 + r;
        const float bo = bias[o];
#pragma unroll
        for (int nb = 0; nb < 4; nb++) {
            const int n = n0 + nb * 16 + l15;
            float v = acc[nb][r] + bo;
            if (mat == 2) {
                Vd[(size_t)o * NN + n] = (bf16_t)v;
            } else {
                int h = o >> 5, d = o & 31;
                bf16_t* dst = (mat == 0) ? Qt : Kt;
                float vv = (mat == 0) ? v * SCALE : v;
                dst[(size_t)h * NN * HD + (size_t)n * HD + d] = (bf16_t)vv;
            }
        }
    }
}

// ---------------------------------------------------------------------------
// Kernel 3: fused attention (flash-style, no max subtraction needed).
// One block = 1 head x 64 query rows; one wave = 16 query rows.
// K-loop in tiles of 32 keys: S = Q K^T (2 MFMA), P = exp(S+bias),
// P -> LDS (C-layout -> A-layout), O += P V (2 MFMA), l += rowsum(P).
// Output Yt (N x 256) bf16 = softmax(QK^T+bias) V, ready as B^T for out proj.
// ---------------------------------------------------------------------------
__global__ __launch_bounds__(256) void k_attn(
    const bf16_t* __restrict__ Qt, const bf16_t* __restrict__ Kt,
    const bf16_t* __restrict__ Vd, const float* __restrict__ emb,
    bf16_t* __restrict__ Yt) {
    __shared__ float lds_emb[40];
    __shared__ bf16_t lds_p[4][16 * 32];
    const int h = blockIdx.x & 7;
    const int qt = blockIdx.x >> 3;
    const int t = threadIdx.x;
    if (t < 37) lds_emb[t] = (t < 36) ? emb[t * HH + h] : 0.0f;
    __syncthreads();

    const int wave = t >> 6, lane = t & 63;
    const int l15 = lane & 15, quad = lane >> 4;
    const int qg0 = qt * 64 + wave * 16;
    const bf16_t* Qh = Qt + (size_t)h * NN * HD;
    const bf16_t* Kh = Kt + (size_t)h * NN * HD;
    const bf16_t* Vh = Vd + (size_t)h * HD * NN;

    const bf8v aq = *(const bf8v*)(Qh + (size_t)(qg0 + l15) * HD + quad * 8);

    int xi[4], yi[4];
#pragma unroll
    for (int r = 0; r < 4; r++) {
        int qi = qg0 + quad * 4 + r;
        xi[r] = qi / NYY;
        yi[r] = qi - xi[r] * NYY;
    }

    f4v o0 = {0.f, 0.f, 0.f, 0.f}, o1 = {0.f, 0.f, 0.f, 0.f};
    const f4v z = {0.f, 0.f, 0.f, 0.f};
    float lsum[4] = {0.f, 0.f, 0.f, 0.f};
    bf16_t* pl = &lds_p[wave][0];

    for (int kb = 0; kb < NN; kb += 32) {
        bf8v kf0 = *(const bf8v*)(Kh + (size_t)(kb + l15) * HD + quad * 8);
        bf8v kf1 = *(const bf8v*)(Kh + (size_t)(kb + 16 + l15) * HD + quad * 8);
        bf8v vf0 = *(const bf8v*)(Vh + (size_t)l15 * NN + kb + quad * 8);
        bf8v vf1 = *(const bf8v*)(Vh + (size_t)(16 + l15) * NN + kb + quad * 8);
        f4v s0 = mfma16(aq, kf0, z);
        f4v s1 = mfma16(aq, kf1, z);
#pragma unroll
        for (int cb = 0; cb < 2; cb++) {
            const f4v& s = cb ? s1 : s0;
            int kj = kb + cb * 16 + l15;
            int xj = kj / NYY;
            int yj = kj - xj * NYY;
#pragma unroll
            for (int r = 0; r < 4; r++) {
                int dx = xi[r] - xj; dx = dx < 0 ? -dx : dx;
                int dy = yi[r] - yj; dy = dy < 0 ? -dy : dy;
                int tok = (dx > 5 || dy > 5) ? 36 : dx * 6 + dy;
                float p = __expf(s[r] + lds_emb[tok]);
                lsum[r] += p;
                pl[(quad * 4 + r) * 32 + cb * 16 + l15] = (bf16_t)p;
            }
        }
        bf8v ap = *(const bf8v*)(pl + l15 * 32 + quad * 8);
        o0 = mfma16(ap, vf0, o0);
        o1 = mfma16(ap, vf1, o1);
    }

#pragma unroll
    for (int r = 0; r < 4; r++) {
        float v = lsum[r];
#pragma unroll
        for (int m = 1; m < 16; m <<= 1) v += __shfl_xor(v, m, 64);
        float inv = 1.0f / v;
        int row = qg0 + quad * 4 + r;
        Yt[(size_t)row * CC + h * HD + l15] = (bf16_t)(o0[r] * inv);
        Yt[(size_t)row * CC + h * HD + 16 + l15] = (bf16_t)(o1[r] * inv);
    }
}

// ---------------------------------------------------------------------------
// Kernel 4: output projection (M=256, N=2304, K=256), fp32 output + bias.
// ---------------------------------------------------------------------------
__global__ __launch_bounds__(256) void k_proj_out(
    const float* __restrict__ Wp, const float* __restrict__ bp,
    const bf16_t* __restrict__ Yt, float* __restrict__ out) {
    const int n0 = blockIdx.x * 64;
    const int o0 = blockIdx.y * 64;
    const int lane = threadIdx.x & 63;
    const int wave = threadIdx.x >> 6;
    const int l15 = lane & 15;
    const int quad = lane >> 4;
    const int orow = o0 + wave * 16;

    f4v acc[4];
#pragma unroll
    for (int i = 0; i < 4; i++) acc[i] = f4v{0.f, 0.f, 0.f, 0.f};

    for (int k0 = 0; k0 < CC; k0 += 32) {
        const float* wp = Wp + (size_t)(orow + l15) * CC + k0 + quad * 8;
        float4 wa = *(const float4*)wp;
        float4 wb = *(const float4*)(wp + 4);
        bf8v af;
        af[0] = (bf16_t)wa.x; af[1] = (bf16_t)wa.y;
        af[2] = (bf16_t)wa.z; af[3] = (bf16_t)wa.w;
        af[4] = (bf16_t)wb.x; af[5] = (bf16_t)wb.y;
        af[6] = (bf16_t)wb.z; af[7] = (bf16_t)wb.w;
#pragma unroll
        for (int nb = 0; nb < 4; nb++) {
            bf8v bv = *(const bf8v*)(Yt + (size_t)(n0 + nb * 16 + l15) * CC + k0 + quad * 8);
            acc[nb] = mfma16(af, bv, acc[nb]);
        }
    }

#pragma unroll
    for (int r = 0; r < 4; r++) {
        const int o = orow + quad * 4 + r;
        const float bo = bp[o];
#pragma unroll
        for (int nb = 0; nb < 4; nb++) {
            const int n = n0 + nb * 16 + l15;
            out[(size_t)o * NN + n] = acc[nb][r] + bo;
        }
    }
}

// ---------------------------------------------------------------------------
extern "C" void kernel_launch(void* const* d_in, const int* in_sizes, int n_in,
                              void* d_out, int out_size, void* d_ws, size_t ws_size,
                              hipStream_t stream) {
    const float* x   = (const float*)d_in[0];
    const float* Wq  = (const float*)d_in[1];
    const float* bq  = (const float*)d_in[2];
    const float* Wk  = (const float*)d_in[3];
    const float* bk  = (const float*)d_in[4];
    const float* Wv  = (const float*)d_in[5];
    const float* bv  = (const float*)d_in[6];
    const float* Wp  = (const float*)d_in[7];
    const float* bp  = (const float*)d_in[8];
    const float* emb = (const float*)d_in[9];
    // d_in[10] = tokens: recomputed analytically in-kernel, never read.
    float* out = (float*)d_out;

    bf16_t* xT = (bf16_t*)d_ws;          // 2304*256 bf16
    bf16_t* Qt = xT + (size_t)NN * CC;   // (H, N, 32)
    bf16_t* Kt = Qt + (size_t)NN * CC;   // (H, N, 32)
    bf16_t* Vd = Kt + (size_t)NN * CC;   // (H, 32, N)
    bf16_t* Yt = Vd + (size_t)NN * CC;   // (N, 256)

    hipLaunchKernelGGL(k_xT, dim3(8 * 36), dim3(256), 0, stream, x, xT);
    hipLaunchKernelGGL(k_proj_qkv, dim3(36, 4, 3), dim3(256), 0, stream,
                       Wq, bq, Wk, bk, Wv, bv, xT, Qt, Kt, Vd);
    hipLaunchKernelGGL(k_attn, dim3(288), dim3(256), 0, stream, Qt, Kt, Vd, emb, Yt);
    hipLaunchKernelGGL(k_proj_out, dim3(36, 4), dim3(256), 0, stream, Wp, bp, Yt, out);
}

// Round 2
// 151.082 us; speedup vs baseline: 1.0659x; 1.0659x over previous
//
#include <hip/hip_runtime.h>

#define NN 2304
#define CC 256
#define HH 8
#define HD 32
#define NYY 48
#define SCALE 0.17677669529663687f

typedef __bf16 bf16_t;
typedef __bf16 bf8v __attribute__((ext_vector_type(8)));
typedef float f4v __attribute__((ext_vector_type(4)));

__device__ __forceinline__ f4v mfma16(bf8v a, bf8v b, f4v c) {
    return __builtin_amdgcn_mfma_f32_16x16x32_bf16(a, b, c, 0, 0, 0);
}

// ---------------------------------------------------------------------------
// Kernel 1 (fused preprocessing):
//   blocks [0,288):   transpose-convert x (256 x 2304 f32) -> xT (2304 x 256 bf16)
//   blocks [288,416): convert Wq|Wk|Wv|Wp (each 256x256 f32) -> Wb bf16 (4x65536)
// ---------------------------------------------------------------------------
__global__ __launch_bounds__(256) void k_pre(
    const float* __restrict__ x, bf16_t* __restrict__ xT,
    const float* __restrict__ Wq, const float* __restrict__ Wk,
    const float* __restrict__ Wv, const float* __restrict__ Wp,
    bf16_t* __restrict__ Wb) {
    const int b = blockIdx.x;
    const int t = threadIdx.x;
    if (b < 288) {
        __shared__ float tile[64][33];
        const int c0 = (b & 7) * 32;
        const int n0 = (b >> 3) * 64;
        const int n = t & 63, cb = t >> 6;
#pragma unroll
        for (int cc = 0; cc < 8; cc++) {
            int c = cc * 4 + cb;
            tile[n][c] = x[(size_t)(c0 + c) * NN + n0 + n];
        }
        __syncthreads();
        const int c = t & 31, nb = t >> 5;
#pragma unroll
        for (int nn = 0; nn < 8; nn++) {
            int n2 = nn * 8 + nb;
            xT[(size_t)(n0 + n2) * CC + c0 + c] = (bf16_t)tile[n2][c];
        }
    } else {
        const int wb = b - 288;
        const int matid = wb >> 5;            // 0..3
        const float* src = (matid == 0) ? Wq : (matid == 1) ? Wk : (matid == 2) ? Wv : Wp;
        const int base = (wb & 31) * 2048 + t * 8;
        float4 a = *(const float4*)(src + base);
        float4 c = *(const float4*)(src + base + 4);
        bf8v o;
        o[0] = (bf16_t)a.x; o[1] = (bf16_t)a.y; o[2] = (bf16_t)a.z; o[3] = (bf16_t)a.w;
        o[4] = (bf16_t)c.x; o[5] = (bf16_t)c.y; o[6] = (bf16_t)c.z; o[7] = (bf16_t)c.w;
        *(bf8v*)(Wb + (size_t)matid * 65536 + base) = o;
    }
}

// ---------------------------------------------------------------------------
// Kernel 2: QKV projection GEMM (M=256 o, N=2304 n, K=256 c), bf16 weights.
// Block: 64 o x 32 n (4 waves, each 16o x 32n, 2 accumulators).
//   Q -> Qt (H, N, 32) pre-scaled; K -> Kt (H, N, 32); V -> Vd (H, 32, N)
// ---------------------------------------------------------------------------
__global__ __launch_bounds__(256) void k_proj_qkv(
    const bf16_t* __restrict__ Wb,
    const float* __restrict__ bq, const float* __restrict__ bk,
    const float* __restrict__ bv,
    const bf16_t* __restrict__ xT,
    bf16_t* __restrict__ Qt, bf16_t* __restrict__ Kt, bf16_t* __restrict__ Vd) {
    const int mat = blockIdx.z;
    const bf16_t* W = Wb + (size_t)mat * 65536;
    const float* bias = (mat == 0) ? bq : (mat == 1) ? bk : bv;
    const int n0 = blockIdx.x * 32;
    const int o0 = blockIdx.y * 64;
    const int lane = threadIdx.x & 63;
    const int wave = threadIdx.x >> 6;
    const int l15 = lane & 15;
    const int quad = lane >> 4;
    const int orow = o0 + wave * 16;

    f4v acc0 = {0.f, 0.f, 0.f, 0.f}, acc1 = {0.f, 0.f, 0.f, 0.f};
#pragma unroll
    for (int k0 = 0; k0 < CC; k0 += 32) {
        bf8v af = *(const bf8v*)(W + (size_t)(orow + l15) * CC + k0 + quad * 8);
        bf8v b0 = *(const bf8v*)(xT + (size_t)(n0 + l15) * CC + k0 + quad * 8);
        bf8v b1 = *(const bf8v*)(xT + (size_t)(n0 + 16 + l15) * CC + k0 + quad * 8);
        acc0 = mfma16(af, b0, acc0);
        acc1 = mfma16(af, b1, acc1);
    }

#pragma unroll
    for (int r = 0; r < 4; r++) {
        const int o = orow + quad * 4 + r;
        const float bo = bias[o];
#pragma unroll
        for (int nb = 0; nb < 2; nb++) {
            const int n = n0 + nb * 16 + l15;
            float v = (nb ? acc1[r] : acc0[r]) + bo;
            if (mat == 2) {
                Vd[(size_t)o * NN + n] = (bf16_t)v;
            } else {
                int h = o >> 5, d = o & 31;
                bf16_t* dst = (mat == 0) ? Qt : Kt;
                float vv = (mat == 0) ? v * SCALE : v;
                dst[(size_t)h * NN * HD + (size_t)n * HD + d] = (bf16_t)vv;
            }
        }
    }
}

// ---------------------------------------------------------------------------
// Kernel 3: split-K fused attention. Grid (288, S). Block = 1 head x 64 q rows,
// key chunk [sidx*L, sidx*L+L). Writes fp32 partial O and partial row-sums.
// ---------------------------------------------------------------------------
__global__ __launch_bounds__(256) void k_attn_split(
    const bf16_t* __restrict__ Qt, const bf16_t* __restrict__ Kt,
    const bf16_t* __restrict__ Vd, const float* __restrict__ emb,
    float* __restrict__ pO, float* __restrict__ pl, int L) {
    __shared__ float lds_emb[40];
    __shared__ bf16_t lds_p[4][16 * 32];
    const int h = blockIdx.x & 7;
    const int qt = blockIdx.x >> 3;
    const int sidx = blockIdx.y;
    const int t = threadIdx.x;
    if (t < 37) lds_emb[t] = (t < 36) ? emb[t * HH + h] : 0.0f;
    __syncthreads();

    const int wave = t >> 6, lane = t & 63;
    const int l15 = lane & 15, quad = lane >> 4;
    const int qg0 = qt * 64 + wave * 16;
    const bf16_t* Qh = Qt + (size_t)h * NN * HD;
    const bf16_t* Kh = Kt + (size_t)h * NN * HD;
    const bf16_t* Vh = Vd + (size_t)h * HD * NN;

    const bf8v aq = *(const bf8v*)(Qh + (size_t)(qg0 + l15) * HD + quad * 8);

    int xi[4], yi[4];
#pragma unroll
    for (int r = 0; r < 4; r++) {
        int qi = qg0 + quad * 4 + r;
        xi[r] = qi / NYY;
        yi[r] = qi - xi[r] * NYY;
    }

    f4v o0 = {0.f, 0.f, 0.f, 0.f}, o1 = {0.f, 0.f, 0.f, 0.f};
    const f4v z = {0.f, 0.f, 0.f, 0.f};
    float lsum[4] = {0.f, 0.f, 0.f, 0.f};
    bf16_t* plds = &lds_p[wave][0];

    const int k_begin = sidx * L, k_end = k_begin + L;
    for (int kb = k_begin; kb < k_end; kb += 32) {
        bf8v kf0 = *(const bf8v*)(Kh + (size_t)(kb + l15) * HD + quad * 8);
        bf8v kf1 = *(const bf8v*)(Kh + (size_t)(kb + 16 + l15) * HD + quad * 8);
        bf8v vf0 = *(const bf8v*)(Vh + (size_t)l15 * NN + kb + quad * 8);
        bf8v vf1 = *(const bf8v*)(Vh + (size_t)(16 + l15) * NN + kb + quad * 8);
        f4v s0 = mfma16(aq, kf0, z);
        f4v s1 = mfma16(aq, kf1, z);
#pragma unroll
        for (int cb = 0; cb < 2; cb++) {
            const f4v& s = cb ? s1 : s0;
            int kj = kb + cb * 16 + l15;
            int xj = kj / NYY;
            int yj = kj - xj * NYY;
#pragma unroll
            for (int r = 0; r < 4; r++) {
                int dx = xi[r] - xj; dx = dx < 0 ? -dx : dx;
                int dy = yi[r] - yj; dy = dy < 0 ? -dy : dy;
                int tok = (dx > 5 || dy > 5) ? 36 : dx * 6 + dy;
                float p = __expf(s[r] + lds_emb[tok]);
                lsum[r] += p;
                plds[(quad * 4 + r) * 32 + cb * 16 + l15] = (bf16_t)p;
            }
        }
        bf8v ap = *(const bf8v*)(plds + l15 * 32 + quad * 8);
        o0 = mfma16(ap, vf0, o0);
        o1 = mfma16(ap, vf1, o1);
    }

    float* pO_s = pO + ((size_t)sidx * HH + h) * NN * HD;
    float* pl_s = pl + ((size_t)sidx * HH + h) * NN;
#pragma unroll
    for (int r = 0; r < 4; r++) {
        float v = lsum[r];
#pragma unroll
        for (int m = 1; m < 16; m <<= 1) v += __shfl_xor(v, m, 64);
        int row = qg0 + quad * 4 + r;
        pO_s[(size_t)row * HD + l15] = o0[r];
        pO_s[(size_t)row * HD + 16 + l15] = o1[r];
        if (l15 == 0) pl_s[row] = v;
    }
}

// ---------------------------------------------------------------------------
// Kernel 4: combine split-K partials -> Yt (N x 256) bf16, normalized.
// One thread per output element; grid 2304 x 256 threads.
// ---------------------------------------------------------------------------
__global__ __launch_bounds__(256) void k_reduce(
    const float* __restrict__ pO, const float* __restrict__ pl,
    bf16_t* __restrict__ Yt, int S) {
    const int e = blockIdx.x * 256 + threadIdx.x;
    const int h = e / (NN * HD);
    const int rem = e - h * (NN * HD);
    const int q = rem >> 5;
    const int d = rem & 31;
    float so = 0.f, sl = 0.f;
    for (int s = 0; s < S; s++) {
        so += pO[((size_t)s * HH + h) * NN * HD + (size_t)q * HD + d];
        sl += pl[((size_t)s * HH + h) * NN + q];
    }
    Yt[(size_t)q * CC + h * HD + d] = (bf16_t)(so / sl);
}

// ---------------------------------------------------------------------------
// Kernel 5: output projection (M=256, N=2304, K=256), bf16 W, fp32 out + bias.
// Block: 64 o x 32 n.
// ---------------------------------------------------------------------------
__global__ __launch_bounds__(256) void k_proj_out(
    const bf16_t* __restrict__ Wb, const float* __restrict__ bp,
    const bf16_t* __restrict__ Yt, float* __restrict__ out) {
    const bf16_t* W = Wb + (size_t)3 * 65536;
    const int n0 = blockIdx.x * 32;
    const int o0 = blockIdx.y * 64;
    const int lane = threadIdx.x & 63;
    const int wave = threadIdx.x >> 6;
    const int l15 = lane & 15;
    const int quad = lane >> 4;
    const int orow = o0 + wave * 16;

    f4v acc0 = {0.f, 0.f, 0.f, 0.f}, acc1 = {0.f, 0.f, 0.f, 0.f};
#pragma unroll
    for (int k0 = 0; k0 < CC; k0 += 32) {
        bf8v af = *(const bf8v*)(W + (size_t)(orow + l15) * CC + k0 + quad * 8);
        bf8v b0 = *(const bf8v*)(Yt + (size_t)(n0 + l15) * CC + k0 + quad * 8);
        bf8v b1 = *(const bf8v*)(Yt + (size_t)(n0 + 16 + l15) * CC + k0 + quad * 8);
        acc0 = mfma16(af, b0, acc0);
        acc1 = mfma16(af, b1, acc1);
    }

#pragma unroll
    for (int r = 0; r < 4; r++) {
        const int o = orow + quad * 4 + r;
        const float bo = bp[o];
        out[(size_t)o * NN + n0 + l15] = acc0[r] + bo;
        out[(size_t)o * NN + n0 + 16 + l15] = acc1[r] + bo;
    }
}

// ---------------------------------------------------------------------------
extern "C" void kernel_launch(void* const* d_in, const int* in_sizes, int n_in,
                              void* d_out, int out_size, void* d_ws, size_t ws_size,
                              hipStream_t stream) {
    const float* x   = (const float*)d_in[0];
    const float* Wq  = (const float*)d_in[1];
    const float* bq  = (const float*)d_in[2];
    const float* Wk  = (const float*)d_in[3];
    const float* bk  = (const float*)d_in[4];
    const float* Wv  = (const float*)d_in[5];
    const float* bv  = (const float*)d_in[6];
    const float* Wp  = (const float*)d_in[7];
    const float* bp  = (const float*)d_in[8];
    const float* emb = (const float*)d_in[9];
    // d_in[10] = tokens: recomputed analytically in-kernel, never read.
    float* out = (float*)d_out;

    bf16_t* xT = (bf16_t*)d_ws;              // NN*CC bf16
    bf16_t* Qt = xT + (size_t)NN * CC;       // (H, N, 32)
    bf16_t* Kt = Qt + (size_t)NN * CC;       // (H, N, 32)
    bf16_t* Vd = Kt + (size_t)NN * CC;       // (H, 32, N)
    bf16_t* Yt = Vd + (size_t)NN * CC;       // (N, 256)
    bf16_t* Wb = Yt + (size_t)NN * CC;       // 4 * 256*256 bf16
    float*  pO = (float*)(Wb + (size_t)4 * CC * CC);  // S * H * N * 32 fp32
    // pl placed after max-S pO to keep layout independent of S choice below.

    const size_t base_bytes = (size_t)5 * NN * CC * 2 + (size_t)4 * CC * CC * 2;
    const size_t per_split = (size_t)HH * NN * HD * 4 + (size_t)HH * NN * 4;
    int S = 1;
    if (base_bytes + 8 * per_split <= ws_size) S = 8;
    else if (base_bytes + 4 * per_split <= ws_size) S = 4;
    else if (base_bytes + 2 * per_split <= ws_size) S = 2;
    float* pl = pO + (size_t)S * HH * NN * HD;
    const int L = NN / S;

    hipLaunchKernelGGL(k_pre, dim3(288 + 128), dim3(256), 0, stream,
                       x, xT, Wq, Wk, Wv, Wp, Wb);
    hipLaunchKernelGGL(k_proj_qkv, dim3(72, 4, 3), dim3(256), 0, stream,
                       Wb, bq, bk, bv, xT, Qt, Kt, Vd);
    hipLaunchKernelGGL(k_attn_split, dim3(288, S), dim3(256), 0, stream,
                       Qt, Kt, Vd, emb, pO, pl, L);
    hipLaunchKernelGGL(k_reduce, dim3((HH * NN * HD) / 256), dim3(256), 0, stream,
                       pO, pl, Yt, S);
    hipLaunchKernelGGL(k_proj_out, dim3(72, 4), dim3(256), 0, stream, Wb, bp, Yt, out);
}